// Round 1
// baseline (371.511 us; speedup 1.0000x reference)
//
#include <hip/hip_runtime.h>
#include <hip/hip_bf16.h>

typedef __attribute__((ext_vector_type(8))) short short8;
typedef __attribute__((ext_vector_type(4))) float f32x4;

#define GLOBAL_AS __attribute__((address_space(1)))
#define LDS_AS    __attribute__((address_space(3)))

__device__ __forceinline__ void async_ld16(const void* g, void* l) {
    __builtin_amdgcn_global_load_lds((const GLOBAL_AS void*)g, (LDS_AS void*)l, 16, 0, 0);
}

__device__ __forceinline__ unsigned short f2bf(float x) {
    union { __hip_bfloat16 h; unsigned short u; } cv;
    cv.h = __float2bfloat16(x);
    return cv.u;
}

// One block per row (D=1024 fixed: 256 threads x float4).
// Rows >= rows_in (padding) write zeros.
__global__ __launch_bounds__(256) void norm_rows_kernel(
    const float* __restrict__ in, unsigned short* __restrict__ outb, int rows_in)
{
    const int row = blockIdx.x;
    const int tid = threadIdx.x;
    float4 v = make_float4(0.f, 0.f, 0.f, 0.f);
    if (row < rows_in)
        v = reinterpret_cast<const float4*>(in + (size_t)row * 1024)[tid];
    float s = v.x * v.x + v.y * v.y + v.z * v.z + v.w * v.w;
    #pragma unroll
    for (int off = 32; off > 0; off >>= 1) s += __shfl_down(s, off);
    __shared__ float sr[4];
    if ((tid & 63) == 0) sr[tid >> 6] = s;
    __syncthreads();
    const float tot = sr[0] + sr[1] + sr[2] + sr[3];
    const float inv = 1.f / fmaxf(sqrtf(tot), 1e-12f);
    ushort4 o;
    o.x = f2bf(v.x * inv);
    o.y = f2bf(v.y * inv);
    o.z = f2bf(v.z * inv);
    o.w = f2bf(v.w * inv);
    reinterpret_cast<ushort4*>(outb + (size_t)row * 1024)[tid] = o;
}

// 128x128 tile, BK=64, 4 waves (2x2), 16x16x32 bf16 MFMA, 4x4 frags/wave.
// Single-buffered LDS, 2-barrier loop (m97 structure).
// LDS layout: [row][slot] where slot = logical_slot ^ (row&7)  (st-style XOR
// swizzle applied on the GLOBAL source side; LDS dest of global_load_lds is
// linear, per rule #21). Epilogue fuses iso = |ds|*sqrt(max(2-2dot,eps))/sqrt2.
__global__ __launch_bounds__(256) void gemm_iso_kernel(
    const unsigned short* __restrict__ A,  // [M][1024] bf16 (normalized features)
    const unsigned short* __restrict__ B,  // [Npad][1024] bf16 (normalized prototypes, zero-padded)
    float* __restrict__ out,               // [M][C]
    const float* __restrict__ ds_ptr,
    int M, int C, int K)
{
    __shared__ __align__(16) char As[128 * 64 * 2];
    __shared__ __align__(16) char Bs[128 * 64 * 2];

    const int tid  = threadIdx.x;
    const int lane = tid & 63;
    const int wid  = tid >> 6;
    const int brow = blockIdx.y * 128;
    const int bcol = blockIdx.x * 128;

    // ---- staging setup: 16 segs of 1024B per operand; wave w owns segs w*4..w*4+3
    const int lrow8 = lane >> 3;            // row within seg (0..7)
    const int slotg = (lane & 7) ^ lrow8;   // pre-swizzled 16B slot in the global row
    const size_t kb = (size_t)K * 2;        // global row stride in bytes

    const char* gA[4]; const char* gB[4]; char* lA[4]; char* lB[4];
    #pragma unroll
    for (int i = 0; i < 4; ++i) {
        const int seg = wid * 4 + i;
        const int r = seg * 8 + lrow8;
        gA[i] = (const char*)A + (size_t)(brow + r) * kb + slotg * 16;
        gB[i] = (const char*)B + (size_t)(bcol + r) * kb + slotg * 16;
        lA[i] = As + seg * 1024;
        lB[i] = Bs + seg * 1024;
    }

    // ---- compute setup
    const int wr = (wid >> 1) * 64;   // wave row offset in tile
    const int wc = (wid & 1) * 64;    // wave col offset in tile
    const int lr = lane & 15;         // row/col within 16x16 fragment
    const int kq = lane >> 4;         // k-quad 0..3
    const int sx = lane & 7;          // read-side swizzle xor (== row&7 since rows step by 16)

    f32x4 zero = {0.f, 0.f, 0.f, 0.f};
    f32x4 acc[4][4];
    #pragma unroll
    for (int m = 0; m < 4; ++m)
        #pragma unroll
        for (int n = 0; n < 4; ++n)
            acc[m][n] = zero;

    int aoff[4], boff[4];
    #pragma unroll
    for (int m = 0; m < 4; ++m) {
        aoff[m] = (wr + m * 16 + lr) * 128;
        boff[m] = (wc + m * 16 + lr) * 128;
    }
    const int so0 = ((0 + kq) ^ sx) * 16;   // kk=0: logical slot kq
    const int so1 = ((4 + kq) ^ sx) * 16;   // kk=1: logical slot 4+kq

    const int ksteps = K >> 6;
    for (int kt = 0; kt < ksteps; ++kt) {
        const size_t koff = (size_t)kt * 128;   // 64 bf16 = 128B per K-step
        #pragma unroll
        for (int i = 0; i < 4; ++i) {
            async_ld16(gA[i] + koff, lA[i]);
            async_ld16(gB[i] + koff, lB[i]);
        }
        __syncthreads();   // drains vmcnt then barrier
        #pragma unroll
        for (int kk = 0; kk < 2; ++kk) {
            const int so = kk ? so1 : so0;
            short8 a[4], b[4];
            #pragma unroll
            for (int m = 0; m < 4; ++m)
                a[m] = *reinterpret_cast<const short8*>(As + aoff[m] + so);
            #pragma unroll
            for (int n = 0; n < 4; ++n)
                b[n] = *reinterpret_cast<const short8*>(Bs + boff[n] + so);
            #pragma unroll
            for (int m = 0; m < 4; ++m)
                #pragma unroll
                for (int n = 0; n < 4; ++n)
                    acc[m][n] = __builtin_amdgcn_mfma_f32_16x16x32_bf16(
                        a[m], b[n], acc[m][n], 0, 0, 0);
        }
        __syncthreads();   // protect LDS before next stage
    }

    // ---- fused epilogue: iso = |ds| * sqrt(max(2-2*dot, 1e-12)) / sqrt(2)
    const float dsv = fabsf(ds_ptr[0]);
    #pragma unroll
    for (int m = 0; m < 4; ++m) {
        const int row0 = brow + wr + m * 16 + kq * 4;   // C/D layout: row=(lane>>4)*4+j
        #pragma unroll
        for (int n = 0; n < 4; ++n) {
            const int col = bcol + wc + n * 16 + lr;     // col = lane&15
            if (col < C) {
                float* op = out + (size_t)row0 * C + col;
                #pragma unroll
                for (int j = 0; j < 4; ++j) {
                    const float sq = fmaxf(2.f - 2.f * acc[m][n][j], 1e-12f);
                    op[(size_t)j * C] = dsv * (sqrtf(sq) * 0.70710678118654752f);
                }
            }
        }
    }
}

// One block per output row: stage the row in LDS, reduce for the mean,
// rewrite logits = -(iso + mean) / temperature. Single read + single write.
__global__ __launch_bounds__(256) void finalize_kernel(
    float* __restrict__ out, const float* __restrict__ tptr, int C)
{
    __shared__ float buf[10240];   // C <= 10240
    __shared__ float sred[4];
    const int row = blockIdx.x;
    const int tid = threadIdx.x;
    float* rp = out + (size_t)row * C;
    const int nv = C >> 2;
    float s = 0.f;
    for (int i = tid; i < nv; i += 256) {
        float4 v = reinterpret_cast<const float4*>(rp)[i];
        reinterpret_cast<float4*>(buf)[i] = v;
        s += (v.x + v.y) + (v.z + v.w);
    }
    for (int i = (nv << 2) + tid; i < C; i += 256) { float v = rp[i]; buf[i] = v; s += v; }
    #pragma unroll
    for (int off = 32; off > 0; off >>= 1) s += __shfl_down(s, off);
    if ((tid & 63) == 0) sred[tid >> 6] = s;
    __syncthreads();
    const float mean = (sred[0] + sred[1] + sred[2] + sred[3]) / (float)C;
    const float invT = 1.f / tptr[0];
    for (int i = tid; i < nv; i += 256) {
        float4 v = reinterpret_cast<const float4*>(buf)[i];
        float4 o;
        o.x = -(v.x + mean) * invT;
        o.y = -(v.y + mean) * invT;
        o.z = -(v.z + mean) * invT;
        o.w = -(v.w + mean) * invT;
        reinterpret_cast<float4*>(rp)[i] = o;
    }
    for (int i = (nv << 2) + tid; i < C; i += 256) rp[i] = -(buf[i] + mean) * invT;
}

extern "C" void kernel_launch(void* const* d_in, const int* in_sizes, int n_in,
                              void* d_out, int out_size, void* d_ws, size_t ws_size,
                              hipStream_t stream)
{
    const float* feat = (const float*)d_in[0];
    const float* prot = (const float*)d_in[1];
    const float* dsc  = (const float*)d_in[2];
    const float* temp = (const float*)d_in[3];
    float* out = (float*)d_out;

    const int D = 1024;
    const int M = in_sizes[0] / D;          // 4096
    const int C = in_sizes[1] / D;          // 10000
    const int NT = (C + 127) / 128;         // 79
    const int Npad = NT * 128;              // 10112

    // ws: bf16 features [M][D] then bf16 prototypes [Npad][D]  (~29.1 MB)
    unsigned short* fbf = (unsigned short*)d_ws;
    unsigned short* pbf = fbf + (size_t)M * D;

    norm_rows_kernel<<<M, 256, 0, stream>>>(feat, fbf, M);
    norm_rows_kernel<<<Npad, 256, 0, stream>>>(prot, pbf, C);
    gemm_iso_kernel<<<dim3(NT, M / 128), 256, 0, stream>>>(fbf, pbf, out, dsc, M, C, D);
    finalize_kernel<<<M, 256, 0, stream>>>(out, temp, C);
}